// Round 1
// baseline (3203.146 us; speedup 1.0000x reference)
//
#include <hip/hip_runtime.h>
#include <math.h>

#define NUM_E 65536
#define NUM_N 8192
#define NUM_G 16
#define RBFR 12.0f

// packed-weight unit counts (one unit = 16B = 8 f16, one lane's B-fragment)
#define U1  139264   // layer-1: 34 ktiles * 64 ntiles * 64 lanes
#define UHL 131072   // per hidden layer: 32 * 64 * 64
#define UH  393216   // 3 hidden layers
#define UPM (U1 + UH)

typedef _Float16 f16x8 __attribute__((ext_vector_type(8)));
typedef _Float16 f16x4 __attribute__((ext_vector_type(4)));
typedef float f32x4 __attribute__((ext_vector_type(4)));

// LDS swizzle: XOR row-dependent bits into 16B-slot bits (short-index bits 3..5)
#define SWZ(row, col) ((((row) * 1088) + (col)) ^ (((row) & 7) << 3))

// ---------- pre-kernel 1: W_rbf = rbf_w @ in_w[1024:1536,:]; b1 = in_b + rbf_b @ in_w[1024:1536,:]
__global__ void wrbf_kernel(const float* __restrict__ rbf_w, const float* __restrict__ rbf_b,
                            const float* __restrict__ e_in_w, const float* __restrict__ e_in_b,
                            const float* __restrict__ f_in_w, const float* __restrict__ f_in_b,
                            float* __restrict__ wrbf_e, float* __restrict__ b1_e,
                            float* __restrict__ wrbf_f, float* __restrict__ b1_f) {
  int blk = blockIdx.x;
  int mlp = blk / 51;
  int row = blk % 51;
  const float* in_w = mlp ? f_in_w : e_in_w;
  const float* in_b = mlp ? f_in_b : e_in_b;
  float* wrbf = mlp ? wrbf_f : wrbf_e;
  float* b1   = mlp ? b1_f : b1_e;
  __shared__ float vec[512];
  for (int i = threadIdx.x; i < 512; i += 256)
    vec[i] = (row < 50) ? rbf_w[row * 512 + i] : rbf_b[i];
  __syncthreads();
  int n0 = threadIdx.x * 4;
  float a0 = 0.f, a1 = 0.f, a2 = 0.f, a3 = 0.f;
  for (int c = 0; c < 512; ++c) {
    const float4 wv = *(const float4*)&in_w[(size_t)(1024 + c) * 1024 + n0];
    float g = vec[c];
    a0 += g * wv.x; a1 += g * wv.y; a2 += g * wv.z; a3 += g * wv.w;
  }
  if (row < 50) {
    float4 o = {a0, a1, a2, a3};
    *(float4*)&wrbf[row * 1024 + n0] = o;
  } else {
    float4 o = {a0 + in_b[n0], a1 + in_b[n0 + 1], a2 + in_b[n0 + 2], a3 + in_b[n0 + 3]};
    *(float4*)&b1[n0] = o;
  }
}

// ---------- pre-kernel 2: pack weights to f16 in B-fragment order
// unit u -> (mlp, layer-1 | hidden(lay), kt, ntg, lane); 8 f16 along k
__global__ void pack_kernel(const float* __restrict__ e_in_w, const float* __restrict__ e_hid_w,
                            const float* __restrict__ f_in_w, const float* __restrict__ f_hid_w,
                            const float* __restrict__ wrbf_e, const float* __restrict__ wrbf_f,
                            unsigned short* __restrict__ wp) {
  int u = blockIdx.x * 256 + threadIdx.x;
  if (u >= 2 * UPM) return;
  int m = (u >= UPM) ? 1 : 0;
  int v = u - m * UPM;
  const float* in_w  = m ? f_in_w : e_in_w;
  const float* hid_w = m ? f_hid_w : e_hid_w;
  const float* wrbf  = m ? wrbf_f : wrbf_e;
  int l = v & 63;
  int kb = (l >> 4) << 3;
  f16x8 vals;
  if (v < U1) {
    int kt = v >> 12;
    int ntg = (v >> 6) & 63;
    int n = ntg * 16 + (l & 15);
    int k0 = kt * 32 + kb;
#pragma unroll
    for (int j = 0; j < 8; ++j) {
      int k = k0 + j;
      float f = (k < 1024) ? in_w[(size_t)k * 1024 + n]
              : ((k < 1074) ? wrbf[(k - 1024) * 1024 + n] : 0.f);
      vals[j] = (_Float16)f;
    }
  } else {
    int vh = v - U1;
    int lay = vh >> 17;
    int kt = (vh >> 12) & 31;
    int ntg = (vh >> 6) & 63;
    int n = ntg * 16 + (l & 15);
    int k0 = kt * 32 + kb;
#pragma unroll
    for (int j = 0; j < 8; ++j)
      vals[j] = (_Float16)hid_w[(size_t)((lay << 10) + k0 + j) * 1024 + n];
  }
  *(f16x8*)(wp + (size_t)u * 8) = vals;
}

// ---------- main fused kernel: 64 edges/block, full 2-MLP pipeline in LDS
__global__ __launch_bounds__(512, 2) void fused_kernel(
    const float* __restrict__ x, const int* __restrict__ eidx,
    const int* __restrict__ batch, const float* __restrict__ dist,
    const float* __restrict__ vhat,
    const unsigned short* __restrict__ wp,
    const float* __restrict__ b1_e, const float* __restrict__ b1_f,
    const float* __restrict__ e_hid_b, const float* __restrict__ f_hid_b,
    const float* __restrict__ e_out_w, const float* __restrict__ e_out_b,
    const float* __restrict__ f_out_w, const float* __restrict__ f_out_b,
    float* __restrict__ out) {
  __shared__ __align__(16) unsigned short Alds[64 * 1088];
  __shared__ float sow[1024];
  __shared__ float sbins[16];
  __shared__ int s_src[64];
  __shared__ int s_dst[64];
  __shared__ float s_dist[64];

  const int tid = threadIdx.x;
  const int lane = tid & 63;
  const int wave = tid >> 6;
  const int e0 = blockIdx.x * 64;

  if (tid < 16) sbins[tid] = 0.f;
  if (tid < 64) s_src[tid] = eidx[e0 + tid];
  if (tid >= 64 && tid < 128) s_dst[tid - 64] = eidx[NUM_E + e0 + tid - 64];
  if (tid >= 128 && tid < 192) s_dist[tid - 128] = dist[e0 + tid - 128];
  __syncthreads();

  const float delta = RBFR / 49.f;
  const float coeff = -0.5f / (delta * delta);

  for (int mlp = 0; mlp < 2; ++mlp) {
    // ---- stage A tile: [64 edges][1088] f16 (x[src] | x[dst] | g-pad64)
    for (int i = tid; i < 16384; i += 512) {
      int e = i >> 8;
      int part = (i >> 7) & 1;
      int q = i & 127;
      int nrow = part ? s_dst[e] : s_src[e];
      float4 v = ((const float4*)x)[(size_t)nrow * 128 + q];
      int col = part * 512 + q * 4;
      f16x4 hv = {(_Float16)v.x, (_Float16)v.y, (_Float16)v.z, (_Float16)v.w};
      *(f16x4*)&Alds[SWZ(e, col)] = hv;
    }
    for (int i = tid; i < 4096; i += 512) {
      int e = i >> 6;
      int gi = i & 63;
      float d = s_dist[e] - (float)gi * delta;
      float g = (gi < 50) ? __expf(coeff * d * d) : 0.f;
      _Float16 hg = (_Float16)g;
      Alds[SWZ(e, 1024 + gi)] = __builtin_bit_cast(unsigned short, hg);
    }
    __syncthreads();

    const unsigned short* wp1 = wp + (size_t)mlp * UPM * 8;
    const unsigned short* wph = wp1 + (size_t)U1 * 8;
    const float* b1 = mlp ? b1_f : b1_e;
    const float* hb = mlp ? f_hid_b : e_hid_b;

    for (int layer = 0; layer < 4; ++layer) {
      const int nkt = (layer == 0) ? 34 : 32;
      const unsigned short* wl = (layer == 0) ? wp1 : (wph + (size_t)(layer - 1) * UHL * 8);
      const float* bias = (layer == 0) ? b1 : (hb + (layer - 1) * 1024);

      f32x4 acc[4][8];
#pragma unroll
      for (int r = 0; r < 4; ++r)
#pragma unroll
        for (int nt = 0; nt < 8; ++nt)
#pragma unroll
          for (int i = 0; i < 4; ++i) acc[r][nt][i] = 0.f;

      for (int kt = 0; kt < nkt; ++kt) {
        f16x8 afrag[4];
        const int kb = kt * 32 + ((lane >> 4) << 3);
#pragma unroll
        for (int r = 0; r < 4; ++r) {
          int row = r * 16 + (lane & 15);
          afrag[r] = *(const f16x8*)&Alds[SWZ(row, kb)];
        }
        const unsigned short* wrow = wl + ((size_t)(kt * 64 + wave * 8) * 64 + lane) * 8;
#pragma unroll
        for (int nt = 0; nt < 8; ++nt) {
          f16x8 bfrag = *(const f16x8*)(wrow + (size_t)nt * 512);
#pragma unroll
          for (int r = 0; r < 4; ++r)
            acc[r][nt] = __builtin_amdgcn_mfma_f32_16x16x32_f16(afrag[r], bfrag, acc[r][nt], 0, 0, 0);
        }
      }
      __syncthreads();   // all waves done reading A/h before overwrite

      float bia[8];
#pragma unroll
      for (int nt = 0; nt < 8; ++nt) bia[nt] = bias[wave * 128 + nt * 16 + (lane & 15)];
#pragma unroll
      for (int r = 0; r < 4; ++r) {
#pragma unroll
        for (int nt = 0; nt < 8; ++nt) {
#pragma unroll
          for (int i = 0; i < 4; ++i) {
            int row = r * 16 + ((lane >> 4) << 2) + i;   // m89 C/D mapping
            int col = wave * 128 + nt * 16 + (lane & 15);
            float pre = acc[r][nt][i] + bia[nt];
            float val = pre / (1.f + __expf(-pre));       // silu
            int idx = SWZ(row, col);
            if (layer > 0) {                               // residual
              _Float16 oldh = __builtin_bit_cast(_Float16, Alds[idx]);
              val += (float)oldh;
            }
            _Float16 nh = (_Float16)val;
            Alds[idx] = __builtin_bit_cast(unsigned short, nh);
          }
        }
      }
      __syncthreads();
    }

    // ---- epilogue: out-dot + scatter
    const float* ow = mlp ? f_out_w : e_out_w;
    for (int i = tid; i < 1024; i += 512) sow[i] = ow[i];
    __syncthreads();
    {
      int e = tid >> 3;
      int part = tid & 7;
      float s = 0.f;
#pragma unroll
      for (int cc = 0; cc < 16; ++cc) {
        int col = part * 128 + cc * 8;
        f16x8 hv = *(const f16x8*)&Alds[SWZ(e, col)];
#pragma unroll
        for (int j = 0; j < 8; ++j) s += (float)hv[j] * sow[col + j];
      }
      s += __shfl_down(s, 4, 8);
      s += __shfl_down(s, 2, 8);
      s += __shfl_down(s, 1, 8);
      if (part == 0) {
        if (mlp == 0) {
          float p = s + e_out_b[0];
          int g = batch[s_src[e]];
          atomicAdd(&sbins[g], p);
        } else {
          float p = (s + f_out_b[0]) * (1.f / 60.f);
          int si = s_src[e];
          float vx = vhat[(size_t)(e0 + e) * 3 + 0];
          float vy = vhat[(size_t)(e0 + e) * 3 + 1];
          float vz = vhat[(size_t)(e0 + e) * 3 + 2];
          atomicAdd(&out[16 + si * 3 + 0], p * vx);
          atomicAdd(&out[16 + si * 3 + 1], p * vy);
          atomicAdd(&out[16 + si * 3 + 2], p * vz);
        }
      }
    }
    __syncthreads();   // epilogue reads done before next mlp restages
  }
  if (tid < 16) atomicAdd(&out[tid], sbins[tid] * (1.f / 3600.f));
}

extern "C" void kernel_launch(void* const* d_in, const int* in_sizes, int n_in,
                              void* d_out, int out_size, void* d_ws, size_t ws_size,
                              hipStream_t stream) {
  (void)in_sizes; (void)n_in; (void)ws_size;
  const float* x      = (const float*)d_in[0];
  const int*   eidx   = (const int*)d_in[1];
  const int*   batch  = (const int*)d_in[2];
  const float* dist   = (const float*)d_in[3];
  const float* vhat   = (const float*)d_in[4];
  const float* rbf_w  = (const float*)d_in[5];
  const float* rbf_b  = (const float*)d_in[6];
  const float* e_in_w = (const float*)d_in[7];
  const float* e_in_b = (const float*)d_in[8];
  const float* e_hid_w = (const float*)d_in[9];
  const float* e_hid_b = (const float*)d_in[10];
  const float* e_out_w = (const float*)d_in[11];
  const float* e_out_b = (const float*)d_in[12];
  const float* f_in_w = (const float*)d_in[13];
  const float* f_in_b = (const float*)d_in[14];
  const float* f_hid_w = (const float*)d_in[15];
  const float* f_hid_b = (const float*)d_in[16];
  const float* f_out_w = (const float*)d_in[17];
  const float* f_out_b = (const float*)d_in[18];

  unsigned short* wp = (unsigned short*)d_ws;               // 2*UPM*8 f16 = 17,039,360 B
  float* wrbf_e = (float*)((char*)d_ws + (size_t)2 * UPM * 8 * 2);
  float* wrbf_f = wrbf_e + 50 * 1024;
  float* b1_e   = wrbf_f + 50 * 1024;
  float* b1_f   = b1_e + 1024;

  hipMemsetAsync(d_out, 0, (size_t)out_size * sizeof(float), stream);
  wrbf_kernel<<<102, 256, 0, stream>>>(rbf_w, rbf_b, e_in_w, e_in_b, f_in_w, f_in_b,
                                       wrbf_e, b1_e, wrbf_f, b1_f);
  pack_kernel<<<(2 * UPM + 255) / 256, 256, 0, stream>>>(e_in_w, e_hid_w, f_in_w, f_hid_w,
                                                         wrbf_e, wrbf_f, wp);
  fused_kernel<<<NUM_E / 64, 512, 0, stream>>>(x, eidx, batch, dist, vhat, wp,
                                               b1_e, b1_f, e_hid_b, f_hid_b,
                                               e_out_w, e_out_b, f_out_w, f_out_b,
                                               (float*)d_out);
}

// Round 2
// 1977.274 us; speedup vs baseline: 1.6200x; 1.6200x over previous
//
#include <hip/hip_runtime.h>
#include <math.h>

#define NUM_E 65536
#define NUM_N 8192
#define NUM_G 16
#define RBFR 12.0f

// packed-weight unit counts (one unit = 16B = 8 f16, one lane's B-fragment)
#define U1  139264   // layer-1: 34 ktiles * 64 ntiles * 64 lanes
#define UHL 131072   // per hidden layer: 32 * 64 * 64
#define UH  393216   // 3 hidden layers
#define UPM (U1 + UH)

typedef _Float16 f16x8 __attribute__((ext_vector_type(8)));
typedef _Float16 f16x4 __attribute__((ext_vector_type(4)));
typedef float f32x4 __attribute__((ext_vector_type(4)));

// LDS swizzle: XOR row-dependent bits into 16B-slot bits (short-index bits 3..5)
#define SWZ(row, col) ((((row) * 1088) + (col)) ^ (((row) & 7) << 3))

// ---------- pre-kernel 1: W_rbf = rbf_w @ in_w[1024:1536,:]; b1 = in_b + rbf_b @ in_w[1024:1536,:]
__global__ void wrbf_kernel(const float* __restrict__ rbf_w, const float* __restrict__ rbf_b,
                            const float* __restrict__ e_in_w, const float* __restrict__ e_in_b,
                            const float* __restrict__ f_in_w, const float* __restrict__ f_in_b,
                            float* __restrict__ wrbf_e, float* __restrict__ b1_e,
                            float* __restrict__ wrbf_f, float* __restrict__ b1_f) {
  int blk = blockIdx.x;
  int mlp = blk / 51;
  int row = blk % 51;
  const float* in_w = mlp ? f_in_w : e_in_w;
  const float* in_b = mlp ? f_in_b : e_in_b;
  float* wrbf = mlp ? wrbf_f : wrbf_e;
  float* b1   = mlp ? b1_f : b1_e;
  __shared__ float vec[512];
  for (int i = threadIdx.x; i < 512; i += 256)
    vec[i] = (row < 50) ? rbf_w[row * 512 + i] : rbf_b[i];
  __syncthreads();
  int n0 = threadIdx.x * 4;
  float a0 = 0.f, a1 = 0.f, a2 = 0.f, a3 = 0.f;
  for (int c = 0; c < 512; ++c) {
    const float4 wv = *(const float4*)&in_w[(size_t)(1024 + c) * 1024 + n0];
    float g = vec[c];
    a0 += g * wv.x; a1 += g * wv.y; a2 += g * wv.z; a3 += g * wv.w;
  }
  if (row < 50) {
    float4 o = {a0, a1, a2, a3};
    *(float4*)&wrbf[row * 1024 + n0] = o;
  } else {
    float4 o = {a0 + in_b[n0], a1 + in_b[n0 + 1], a2 + in_b[n0 + 2], a3 + in_b[n0 + 3]};
    *(float4*)&b1[n0] = o;
  }
}

// ---------- pre-kernel 2: pack weights to f16 in B-fragment order
__global__ void pack_kernel(const float* __restrict__ e_in_w, const float* __restrict__ e_hid_w,
                            const float* __restrict__ f_in_w, const float* __restrict__ f_hid_w,
                            const float* __restrict__ wrbf_e, const float* __restrict__ wrbf_f,
                            unsigned short* __restrict__ wp) {
  int u = blockIdx.x * 256 + threadIdx.x;
  if (u >= 2 * UPM) return;
  int m = (u >= UPM) ? 1 : 0;
  int v = u - m * UPM;
  const float* in_w  = m ? f_in_w : e_in_w;
  const float* hid_w = m ? f_hid_w : e_hid_w;
  const float* wrbf  = m ? wrbf_f : wrbf_e;
  int l = v & 63;
  int kb = (l >> 4) << 3;
  f16x8 vals;
  if (v < U1) {
    int kt = v >> 12;
    int ntg = (v >> 6) & 63;
    int n = ntg * 16 + (l & 15);
    int k0 = kt * 32 + kb;
#pragma unroll
    for (int j = 0; j < 8; ++j) {
      int k = k0 + j;
      float f = (k < 1024) ? in_w[(size_t)k * 1024 + n]
              : ((k < 1074) ? wrbf[(k - 1024) * 1024 + n] : 0.f);
      vals[j] = (_Float16)f;
    }
  } else {
    int vh = v - U1;
    int lay = vh >> 17;
    int kt = (vh >> 12) & 31;
    int ntg = (vh >> 6) & 63;
    int n = ntg * 16 + (l & 15);
    int k0 = kt * 32 + kb;
#pragma unroll
    for (int j = 0; j < 8; ++j)
      vals[j] = (_Float16)hid_w[(size_t)((lay << 10) + k0 + j) * 1024 + n];
  }
  *(f16x8*)(wp + (size_t)u * 8) = vals;
}

// pipelined fragment load/compute macros (named buffers -> static reg indexing)
#define LOADB(buf, kt) do { \
  const unsigned short* _wr = wl + ((size_t)((kt) * 64 + wave * 8) * 64 + lane) * 8; \
  _Pragma("unroll") \
  for (int _nt = 0; _nt < 8; ++_nt) buf[_nt] = *(const f16x8*)(_wr + (size_t)_nt * 512); \
} while (0)

#define LOADA(buf, kt) do { \
  const int _kb = (kt) * 32 + ((lane >> 4) << 3); \
  _Pragma("unroll") \
  for (int _r = 0; _r < 4; ++_r) buf[_r] = *(const f16x8*)&Alds[SWZ(_r * 16 + (lane & 15), _kb)]; \
} while (0)

#define MFMAS(abuf, bbuf) do { \
  _Pragma("unroll") \
  for (int _nt = 0; _nt < 8; ++_nt) \
    _Pragma("unroll") \
    for (int _r = 0; _r < 4; ++_r) \
      acc[_r][_nt] = __builtin_amdgcn_mfma_f32_16x16x32_f16(abuf[_r], bbuf[_nt], acc[_r][_nt], 0, 0, 0); \
} while (0)

// ---------- main fused kernel: 64 edges/block, full 2-MLP pipeline in LDS
__global__ __launch_bounds__(512, 2) void fused_kernel(
    const float* __restrict__ x, const int* __restrict__ eidx,
    const int* __restrict__ batch, const float* __restrict__ dist,
    const float* __restrict__ vhat,
    const unsigned short* __restrict__ wp,
    const float* __restrict__ b1_e, const float* __restrict__ b1_f,
    const float* __restrict__ e_hid_b, const float* __restrict__ f_hid_b,
    const float* __restrict__ e_out_w, const float* __restrict__ e_out_b,
    const float* __restrict__ f_out_w, const float* __restrict__ f_out_b,
    float* __restrict__ out) {
  __shared__ __align__(16) unsigned short Alds[64 * 1088];
  __shared__ float sow[1024];
  __shared__ float sbins[16];
  __shared__ int s_src[64];
  __shared__ int s_dst[64];
  __shared__ float s_dist[64];

  const int tid = threadIdx.x;
  const int lane = tid & 63;
  const int wave = tid >> 6;
  const int e0 = blockIdx.x * 64;

  if (tid < 16) sbins[tid] = 0.f;
  if (tid < 64) s_src[tid] = eidx[e0 + tid];
  if (tid >= 64 && tid < 128) s_dst[tid - 64] = eidx[NUM_E + e0 + tid - 64];
  if (tid >= 128 && tid < 192) s_dist[tid - 128] = dist[e0 + tid - 128];
  __syncthreads();

  const float delta = RBFR / 49.f;
  const float coeff = -0.5f / (delta * delta);

  for (int mlp = 0; mlp < 2; ++mlp) {
    // ---- stage A tile: [64 edges][1088] f16 (x[src] | x[dst] | g-pad64)
    for (int i = tid; i < 16384; i += 512) {
      int e = i >> 8;
      int part = (i >> 7) & 1;
      int q = i & 127;
      int nrow = part ? s_dst[e] : s_src[e];
      float4 v = ((const float4*)x)[(size_t)nrow * 128 + q];
      int col = part * 512 + q * 4;
      f16x4 hv = {(_Float16)v.x, (_Float16)v.y, (_Float16)v.z, (_Float16)v.w};
      *(f16x4*)&Alds[SWZ(e, col)] = hv;
    }
    for (int i = tid; i < 4096; i += 512) {
      int e = i >> 6;
      int gi = i & 63;
      float d = s_dist[e] - (float)gi * delta;
      float g = (gi < 50) ? __expf(coeff * d * d) : 0.f;
      _Float16 hg = (_Float16)g;
      Alds[SWZ(e, 1024 + gi)] = __builtin_bit_cast(unsigned short, hg);
    }
    __syncthreads();

    const unsigned short* wp1 = wp + (size_t)mlp * UPM * 8;
    const unsigned short* wph = wp1 + (size_t)U1 * 8;
    const float* b1 = mlp ? b1_f : b1_e;
    const float* hb = mlp ? f_hid_b : e_hid_b;

    for (int layer = 0; layer < 4; ++layer) {
      const int nkt = (layer == 0) ? 34 : 32;
      const unsigned short* wl = (layer == 0) ? wp1 : (wph + (size_t)(layer - 1) * UHL * 8);
      const float* bias = (layer == 0) ? b1 : (hb + (layer - 1) * 1024);

      f32x4 acc[4][8];
#pragma unroll
      for (int r = 0; r < 4; ++r)
#pragma unroll
        for (int nt = 0; nt < 8; ++nt)
#pragma unroll
          for (int i = 0; i < 4; ++i) acc[r][nt][i] = 0.f;

      // 2-deep software-pipelined K loop: loads for kt+2/kt+3 issue under
      // the MFMA clusters for kt/kt+1 (covers L2/LLC latency at 2 waves/SIMD)
      f16x8 a0[4], a1[4], b0[8], b1r[8];
      LOADA(a0, 0); LOADB(b0, 0);
      LOADA(a1, 1); LOADB(b1r, 1);
      for (int kt = 0; kt < nkt; kt += 2) {
        MFMAS(a0, b0);
        if (kt + 2 < nkt) { LOADA(a0, kt + 2); LOADB(b0, kt + 2); }
        MFMAS(a1, b1r);
        if (kt + 3 < nkt) { LOADA(a1, kt + 3); LOADB(b1r, kt + 3); }
      }
      __syncthreads();   // all waves done reading A/h before overwrite

      float bia[8];
#pragma unroll
      for (int nt = 0; nt < 8; ++nt) bia[nt] = bias[wave * 128 + nt * 16 + (lane & 15)];
#pragma unroll
      for (int r = 0; r < 4; ++r) {
#pragma unroll
        for (int nt = 0; nt < 8; ++nt) {
#pragma unroll
          for (int i = 0; i < 4; ++i) {
            int row = r * 16 + ((lane >> 4) << 2) + i;   // m89 C/D mapping
            int col = wave * 128 + nt * 16 + (lane & 15);
            float pre = acc[r][nt][i] + bia[nt];
            float val = pre / (1.f + __expf(-pre));       // silu
            int idx = SWZ(row, col);
            if (layer > 0) {                               // residual
              _Float16 oldh = __builtin_bit_cast(_Float16, Alds[idx]);
              val += (float)oldh;
            }
            _Float16 nh = (_Float16)val;
            Alds[idx] = __builtin_bit_cast(unsigned short, nh);
          }
        }
      }
      __syncthreads();
    }

    // ---- epilogue: out-dot + scatter
    const float* ow = mlp ? f_out_w : e_out_w;
    for (int i = tid; i < 1024; i += 512) sow[i] = ow[i];
    __syncthreads();
    {
      int e = tid >> 3;
      int part = tid & 7;
      float s = 0.f;
#pragma unroll
      for (int cc = 0; cc < 16; ++cc) {
        int col = part * 128 + cc * 8;
        f16x8 hv = *(const f16x8*)&Alds[SWZ(e, col)];
#pragma unroll
        for (int j = 0; j < 8; ++j) s += (float)hv[j] * sow[col + j];
      }
      s += __shfl_down(s, 4, 8);
      s += __shfl_down(s, 2, 8);
      s += __shfl_down(s, 1, 8);
      if (part == 0) {
        if (mlp == 0) {
          float p = s + e_out_b[0];
          int g = batch[s_src[e]];
          atomicAdd(&sbins[g], p);
        } else {
          float p = (s + f_out_b[0]) * (1.f / 60.f);
          int si = s_src[e];
          float vx = vhat[(size_t)(e0 + e) * 3 + 0];
          float vy = vhat[(size_t)(e0 + e) * 3 + 1];
          float vz = vhat[(size_t)(e0 + e) * 3 + 2];
          atomicAdd(&out[16 + si * 3 + 0], p * vx);
          atomicAdd(&out[16 + si * 3 + 1], p * vy);
          atomicAdd(&out[16 + si * 3 + 2], p * vz);
        }
      }
    }
    __syncthreads();   // epilogue reads done before next mlp restages
  }
  if (tid < 16) atomicAdd(&out[tid], sbins[tid] * (1.f / 3600.f));
}

extern "C" void kernel_launch(void* const* d_in, const int* in_sizes, int n_in,
                              void* d_out, int out_size, void* d_ws, size_t ws_size,
                              hipStream_t stream) {
  (void)in_sizes; (void)n_in; (void)ws_size;
  const float* x      = (const float*)d_in[0];
  const int*   eidx   = (const int*)d_in[1];
  const int*   batch  = (const int*)d_in[2];
  const float* dist   = (const float*)d_in[3];
  const float* vhat   = (const float*)d_in[4];
  const float* rbf_w  = (const float*)d_in[5];
  const float* rbf_b  = (const float*)d_in[6];
  const float* e_in_w = (const float*)d_in[7];
  const float* e_in_b = (const float*)d_in[8];
  const float* e_hid_w = (const float*)d_in[9];
  const float* e_hid_b = (const float*)d_in[10];
  const float* e_out_w = (const float*)d_in[11];
  const float* e_out_b = (const float*)d_in[12];
  const float* f_in_w = (const float*)d_in[13];
  const float* f_in_b = (const float*)d_in[14];
  const float* f_hid_w = (const float*)d_in[15];
  const float* f_hid_b = (const float*)d_in[16];
  const float* f_out_w = (const float*)d_in[17];
  const float* f_out_b = (const float*)d_in[18];

  unsigned short* wp = (unsigned short*)d_ws;               // 2*UPM*8 f16 = 17,039,360 B
  float* wrbf_e = (float*)((char*)d_ws + (size_t)2 * UPM * 8 * 2);
  float* wrbf_f = wrbf_e + 50 * 1024;
  float* b1_e   = wrbf_f + 50 * 1024;
  float* b1_f   = b1_e + 1024;

  hipMemsetAsync(d_out, 0, (size_t)out_size * sizeof(float), stream);
  wrbf_kernel<<<102, 256, 0, stream>>>(rbf_w, rbf_b, e_in_w, e_in_b, f_in_w, f_in_b,
                                       wrbf_e, b1_e, wrbf_f, b1_f);
  pack_kernel<<<(2 * UPM + 255) / 256, 256, 0, stream>>>(e_in_w, e_hid_w, f_in_w, f_hid_w,
                                                         wrbf_e, wrbf_f, wp);
  fused_kernel<<<NUM_E / 64, 512, 0, stream>>>(x, eidx, batch, dist, vhat, wp,
                                               b1_e, b1_f, e_hid_b, f_hid_b,
                                               e_out_w, e_out_b, f_out_w, f_out_b,
                                               (float*)d_out);
}